// Round 9
// baseline (41.984 us; speedup 1.0000x reference)
//
#include <hip/hip_runtime.h>
#include <cfloat>

#define SS 900      // sequence length (30*30)
#define WD 8
#define BD 8
#define NROWS 64    // B*W
#define OUT_ELEMS (BD * SS * WD)  // 57600
#define NQ 225      // float4s per row (900/4)
#define ROWS_PER_BLK 16
#define BLKS_PER_N 57             // ceil(900/16)
#define CAP 128                   // candidate queue capacity per block

typedef float vf4 __attribute__((ext_vector_type(4)));

// One block = 16 rows (16 lanes each) of one n; k staged in LDS.
// Stream pass keeps only per-j maxima M[15] + D (no U storage -> low VGPR);
// gumbel is loaded NON-TEMPORALLY (zero-reuse stream, skip cache fills).
// After the monotone-inversion u-threshold is known, qualifying j's re-load
// their float4 and push candidates to an LDS queue; ONE convergent libm
// eval pass scores them; per-row winner via 64-bit atomicMax with
// (orderable-float-key, ~s) packing (first-index tie-break).
// Winner INDEX goes to idxbuf (no global scatter; out handled by rel_final).
__global__ __launch_bounds__(256) void rel_main(
    const float* __restrict__ radar,   // [W,B,900]
    const float* __restrict__ mde,     // [W,B,900]
    const float* __restrict__ gumbel,  // [N,900,900]
    const float* __restrict__ pWq, const float* __restrict__ pbq,
    const float* __restrict__ pWk, const float* __restrict__ pbk,
    int* __restrict__ idxbuf)          // [64][900]
{
    const int tid   = threadIdx.x;
    const int n     = blockIdx.x / BLKS_PER_N;
    const int tbase = (blockIdx.x - n * BLKS_PER_N) * ROWS_PER_BLK;
    const int b     = n >> 3;          // n = b*W + w
    const int w     = n & 7;

    __shared__ float4 ks4[NQ + 1];
    __shared__ float  s_red[8];
    __shared__ float  s_q[ROWS_PER_BLK], s_m[ROWS_PER_BLK], s_D[ROWS_PER_BLK];
    __shared__ unsigned long long s_win[ROWS_PER_BLK];
    __shared__ int    s_cnt;
    __shared__ int    s_qs[CAP];
    __shared__ float  s_qu[CAP];

    if (tid == 0) s_cnt = 0;
    if (tid < ROWS_PER_BLK) s_win[tid] = 0ULL;

    // ---- stage k = fl(mde*Wk + bk) into LDS; exact block min/max ----
    const float wk = pWk[0], bk0 = pbk[0];
    float kmin = FLT_MAX, kmax = -FLT_MAX;
    if (tid < NQ) {
        const float4* __restrict__ m4p = (const float4*)(mde + (size_t)(w * BD + b) * SS);
        float4 mq = m4p[tid];
        float4 k;
        k.x = __fmaf_rn(mq.x, wk, bk0);
        k.y = __fmaf_rn(mq.y, wk, bk0);
        k.z = __fmaf_rn(mq.z, wk, bk0);
        k.w = __fmaf_rn(mq.w, wk, bk0);
        ks4[tid] = k;
        kmin = fminf(fminf(k.x, k.y), fminf(k.z, k.w));
        kmax = fmaxf(fmaxf(k.x, k.y), fmaxf(k.z, k.w));
    }
    #pragma unroll
    for (int off = 1; off < 64; off <<= 1) {
        kmin = fminf(kmin, __shfl_xor(kmin, off, 64));
        kmax = fmaxf(kmax, __shfl_xor(kmax, off, 64));
    }
    if ((tid & 63) == 0) { s_red[tid >> 6] = kmin; s_red[4 + (tid >> 6)] = kmax; }
    __syncthreads();
    kmin = fminf(fminf(s_red[0], s_red[1]), fminf(s_red[2], s_red[3]));
    kmax = fmaxf(fmaxf(s_red[4], s_red[5]), fmaxf(s_red[6], s_red[7]));

    const int gg     = tid >> 4;
    const int lane16 = tid & 15;
    const int t      = tbase + gg;
    const bool active = (t < SS);
    const int tc     = active ? t : 0;       // tail groups do harmless work
    const int row    = n * SS + tc;

    const float r0 = radar[(size_t)(w * BD + b) * SS + tc];
    const float q  = __fmaf_rn(r0, pWq[0], pbq[0]);
    // max_s fl(q*k_s) == fl(q*k_ext) by monotonicity of rounding
    const float m  = __fmul_rn(q, (q >= 0.0f) ? kmax : kmin);

    const vf4*    __restrict__ g4 = (const vf4*)(gumbel + (size_t)row * SS);
    const float*  __restrict__ kf = (const float*)ks4;

    // ---- stream: per-j max M[j] + D = sum __expf(q*k - m) ----
    float M[15];
    float D = 0.0f;
    #pragma unroll
    for (int j = 0; j < 15; j++) {
        const int f = j * 16 + lane16;
        const bool valid = (j < 14) || (lane16 == 0);   // 225 = 14*16 + 1
        const int fc = valid ? f : 0;
        vf4 u = __builtin_nontemporal_load(&g4[fc]);    // zero-reuse stream
        float4 k = ks4[fc];
        if (!valid) { u[0] = u[1] = u[2] = u[3] = -1.0f; }
        M[j] = fmaxf(fmaxf(u[0], u[1]), fmaxf(u[2], u[3]));
        if (valid) {
            D += __expf(__fmaf_rn(q, k.x, -m)) + __expf(__fmaf_rn(q, k.y, -m))
               + __expf(__fmaf_rn(q, k.z, -m)) + __expf(__fmaf_rn(q, k.w, -m));
        }
    }
    float umax = M[0];
    #pragma unroll
    for (int j = 1; j < 15; j++) umax = fmaxf(umax, M[j]);
    #pragma unroll
    for (int off = 1; off < 16; off <<= 1) {
        umax = fmaxf(umax, __shfl_xor(umax, off, 16));
        D += __shfl_xor(D, off, 16);
    }
    if (active && lane16 == 0) { s_q[gg] = q; s_m[gg] = m; s_D[gg] = D; }

    // ---- u-threshold: winner has nz >= nzmax - margin, margin ~ 1/D ----
    // nz(u) >= T  <=>  u >= exp(-(exp(-T) - 1e-8)) - 1e-8   (monotone).
    // hw __logf/__expf here: filter is inclusive; 1e-5 rel downward fudge
    // absorbs hw-trans error. Precise eval below stays libm.
    float margin = __fmaf_rn(1.002f, 1.0f / D, 1e-6f);
    float w0    = -__logf(umax + 1e-8f);
    float nzmax = -__logf(w0 + 1e-8f);
    float T     = nzmax - margin;
    float wT    = __expf(-T);
    float uthr  = __expf(-(wT - 1e-8f)) - 1e-8f;
    uthr = uthr - fabsf(uthr) * 1e-5f - 1e-9f;   // downward: inclusive filter

    // ---- scan M[]; qualifying j re-loads its float4 and pushes candidates ----
    if (active) {
        #pragma unroll
        for (int j = 0; j < 15; j++) {
            if (M[j] >= uthr) {
                const int f = j * 16 + lane16;
                const bool valid = (j < 14) || (lane16 == 0);
                const int fc = valid ? f : 0;
                vf4 u = g4[fc];                    // rare re-read
                if (!valid) { u[0] = u[1] = u[2] = u[3] = -1.0f; }
                const int s0 = fc * 4;
                if (u[0] >= uthr) { int i2 = atomicAdd(&s_cnt, 1); if (i2 < CAP) { s_qs[i2] = (gg << 10) | s0;       s_qu[i2] = u[0]; } }
                if (u[1] >= uthr) { int i2 = atomicAdd(&s_cnt, 1); if (i2 < CAP) { s_qs[i2] = (gg << 10) | (s0 + 1); s_qu[i2] = u[1]; } }
                if (u[2] >= uthr) { int i2 = atomicAdd(&s_cnt, 1); if (i2 < CAP) { s_qs[i2] = (gg << 10) | (s0 + 2); s_qu[i2] = u[2]; } }
                if (u[3] >= uthr) { int i2 = atomicAdd(&s_cnt, 1); if (i2 < CAP) { s_qs[i2] = (gg << 10) | (s0 + 3); s_qu[i2] = u[3]; } }
            }
        }
    }
    __syncthreads();

    // ---- ONE convergent precise eval pass over the block's candidates ----
    const int nc = min(s_cnt, CAP);
    if (tid < nc) {
        int   pk = s_qs[tid];
        int   g2 = pk >> 10, s = pk & 0x3FF;
        float u  = s_qu[tid];
        float q2 = s_q[g2], m2 = s_m[g2], D2 = s_D[g2];
        float l  = __fmul_rn(q2, kf[s]);
        float nz = -logf(-logf(u + 1e-8f) + 1e-8f);
        float v  = expf(l - m2) / D2 + nz;
        unsigned vb = __float_as_uint(v);
        unsigned key32 = (vb & 0x80000000u) ? ~vb : (vb | 0x80000000u);
        unsigned long long key =
            ((unsigned long long)key32 << 32) | (unsigned)(0xFFFFFFFFu - (unsigned)s);
        atomicMax(&s_win[g2], key);
    }
    __syncthreads();

    if (active && lane16 == 0) {
        unsigned long long key = s_win[gg];
        unsigned s = 0xFFFFFFFFu - (unsigned)(key & 0xFFFFFFFFull);
        idxbuf[n * SS + t] = (int)s;
    }
}

// One block per n: gather radar[t] into acc[idx[t]] via LDS atomics, then
// write EVERY out element with the epilogue fused (no pre-zero, no RMW):
// out[b,s,w] = acc[s] + (radar[s]!=0 && acc[s]!=0) * scale*beta
__global__ __launch_bounds__(256) void rel_final(
    const float* __restrict__ radar,   // [W,B,900]
    const int* __restrict__ idxbuf,    // [64][900]
    const float* __restrict__ pScale,
    const float* __restrict__ pBeta,
    float* __restrict__ out)           // [B,900,W]
{
    const int n = blockIdx.x;
    const int b = n >> 3, w = n & 7;
    const int tid = threadIdx.x;

    __shared__ float acc[SS];
    __shared__ float rad[SS];

    #pragma unroll
    for (int s = tid; s < SS; s += 256) {
        acc[s] = 0.0f;
        rad[s] = radar[(size_t)(w * BD + b) * SS + s];
    }
    __syncthreads();
    #pragma unroll
    for (int t = tid; t < SS; t += 256)
        atomicAdd(&acc[idxbuf[n * SS + t]], rad[t]);
    __syncthreads();
    const float c = pScale[0] * pBeta[0];
    #pragma unroll
    for (int s = tid; s < SS; s += 256) {
        float o = acc[s];
        float r = rad[s];
        out[((size_t)b * SS + s) * WD + w] =
            o + (((r != 0.0f) && (o != 0.0f)) ? c : 0.0f);
    }
}

extern "C" void kernel_launch(void* const* d_in, const int* in_sizes, int n_in,
                              void* d_out, int out_size, void* d_ws, size_t ws_size,
                              hipStream_t stream) {
    const float* radar  = (const float*)d_in[0];
    const float* mde    = (const float*)d_in[1];
    const float* gumbel = (const float*)d_in[2];
    const float* Wq     = (const float*)d_in[3];
    const float* bq     = (const float*)d_in[4];
    const float* Wk     = (const float*)d_in[5];
    const float* bk     = (const float*)d_in[6];
    // d_in[7..11] = Wv, bv, Wo, bo, ln_gamma (dead: LN over dim-1 => attended_out == ln_beta)
    const float* beta   = (const float*)d_in[12];
    const float* scale  = (const float*)d_in[13];
    float* out = (float*)d_out;

    int* idxbuf = (int*)d_ws;          // [64][900], fully overwritten each call

    rel_main<<<NROWS * BLKS_PER_N, 256, 0, stream>>>(radar, mde, gumbel,
                                                     Wq, bq, Wk, bk, idxbuf);
    rel_final<<<NROWS, 256, 0, stream>>>(radar, idxbuf, scale, beta, out);
}

// Round 10
// 41.198 us; speedup vs baseline: 1.0191x; 1.0191x over previous
//
#include <hip/hip_runtime.h>
#include <cfloat>

#define SS 900      // sequence length (30*30)
#define WD 8
#define BD 8
#define NROWS 64    // B*W
#define OUT_ELEMS (BD * SS * WD)  // 57600
#define NQ 225      // float4s per row (900/4)
#define ROWS_PER_BLK 16
#define BLKS_PER_N 57             // ceil(900/16)
#define CAP 128                   // candidate queue capacity per block

// One block = 16 rows (16 lanes each) of one n; k staged in LDS.
// Stream pass keeps only per-j maxima M[15] + D (no U storage -> low VGPR).
// After the monotone-inversion u-threshold is known, qualifying j's re-load
// their float4 (L1/L2-hot) and push candidates to an LDS queue; ONE
// convergent libm eval pass scores them; per-row winner via 64-bit atomicMax
// with (orderable-float-key, ~s) packing (first-index tie-break).
// Winner INDEX goes to idxbuf (no global scatter; out handled by rel_final).
__global__ __launch_bounds__(256) void rel_main(
    const float* __restrict__ radar,   // [W,B,900]
    const float* __restrict__ mde,     // [W,B,900]
    const float* __restrict__ gumbel,  // [N,900,900]
    const float* __restrict__ pWq, const float* __restrict__ pbq,
    const float* __restrict__ pWk, const float* __restrict__ pbk,
    int* __restrict__ idxbuf)          // [64][900]
{
    const int tid   = threadIdx.x;
    const int n     = blockIdx.x / BLKS_PER_N;
    const int tbase = (blockIdx.x - n * BLKS_PER_N) * ROWS_PER_BLK;
    const int b     = n >> 3;          // n = b*W + w
    const int w     = n & 7;

    __shared__ float4 ks4[NQ + 1];
    __shared__ float  s_red[8];
    __shared__ float  s_q[ROWS_PER_BLK], s_m[ROWS_PER_BLK], s_D[ROWS_PER_BLK];
    __shared__ unsigned long long s_win[ROWS_PER_BLK];
    __shared__ int    s_cnt;
    __shared__ int    s_qs[CAP];
    __shared__ float  s_qu[CAP];

    if (tid == 0) s_cnt = 0;
    if (tid < ROWS_PER_BLK) s_win[tid] = 0ULL;

    // ---- stage k = fl(mde*Wk + bk) into LDS; exact block min/max ----
    const float wk = pWk[0], bk0 = pbk[0];
    float kmin = FLT_MAX, kmax = -FLT_MAX;
    if (tid < NQ) {
        const float4* __restrict__ m4p = (const float4*)(mde + (size_t)(w * BD + b) * SS);
        float4 mq = m4p[tid];
        float4 k;
        k.x = __fmaf_rn(mq.x, wk, bk0);
        k.y = __fmaf_rn(mq.y, wk, bk0);
        k.z = __fmaf_rn(mq.z, wk, bk0);
        k.w = __fmaf_rn(mq.w, wk, bk0);
        ks4[tid] = k;
        kmin = fminf(fminf(k.x, k.y), fminf(k.z, k.w));
        kmax = fmaxf(fmaxf(k.x, k.y), fmaxf(k.z, k.w));
    }
    #pragma unroll
    for (int off = 1; off < 64; off <<= 1) {
        kmin = fminf(kmin, __shfl_xor(kmin, off, 64));
        kmax = fmaxf(kmax, __shfl_xor(kmax, off, 64));
    }
    if ((tid & 63) == 0) { s_red[tid >> 6] = kmin; s_red[4 + (tid >> 6)] = kmax; }
    __syncthreads();
    kmin = fminf(fminf(s_red[0], s_red[1]), fminf(s_red[2], s_red[3]));
    kmax = fmaxf(fmaxf(s_red[4], s_red[5]), fmaxf(s_red[6], s_red[7]));

    const int gg     = tid >> 4;
    const int lane16 = tid & 15;
    const int t      = tbase + gg;
    const bool active = (t < SS);
    const int tc     = active ? t : 0;       // tail groups do harmless work
    const int row    = n * SS + tc;

    const float r0 = radar[(size_t)(w * BD + b) * SS + tc];
    const float q  = __fmaf_rn(r0, pWq[0], pbq[0]);
    // max_s fl(q*k_s) == fl(q*k_ext) by monotonicity of rounding
    const float m  = __fmul_rn(q, (q >= 0.0f) ? kmax : kmin);

    const float4* __restrict__ g4 = (const float4*)(gumbel + (size_t)row * SS);
    const float*  __restrict__ kf = (const float*)ks4;

    // ---- stream: per-j max M[j] + D = sum __expf(q*k - m) ----
    float M[15];
    float D = 0.0f;
    #pragma unroll
    for (int j = 0; j < 15; j++) {
        const int f = j * 16 + lane16;
        const bool valid = (j < 14) || (lane16 == 0);   // 225 = 14*16 + 1
        const int fc = valid ? f : 0;
        float4 u = g4[fc];
        float4 k = ks4[fc];
        if (!valid) { u.x = u.y = u.z = u.w = -1.0f; }
        M[j] = fmaxf(fmaxf(u.x, u.y), fmaxf(u.z, u.w));
        if (valid) {
            D += __expf(__fmaf_rn(q, k.x, -m)) + __expf(__fmaf_rn(q, k.y, -m))
               + __expf(__fmaf_rn(q, k.z, -m)) + __expf(__fmaf_rn(q, k.w, -m));
        }
    }
    float umax = M[0];
    #pragma unroll
    for (int j = 1; j < 15; j++) umax = fmaxf(umax, M[j]);
    #pragma unroll
    for (int off = 1; off < 16; off <<= 1) {
        umax = fmaxf(umax, __shfl_xor(umax, off, 16));
        D += __shfl_xor(D, off, 16);
    }
    if (active && lane16 == 0) { s_q[gg] = q; s_m[gg] = m; s_D[gg] = D; }

    // ---- u-threshold: winner has nz >= nzmax - margin, margin ~ 1/D ----
    // nz(u) >= T  <=>  u >= exp(-(exp(-T) - 1e-8)) - 1e-8   (monotone).
    // hw __logf/__expf here: filter is inclusive; 1e-5 rel downward fudge
    // absorbs hw-trans error. Precise eval below stays libm.
    float margin = __fmaf_rn(1.002f, 1.0f / D, 1e-6f);
    float w0    = -__logf(umax + 1e-8f);
    float nzmax = -__logf(w0 + 1e-8f);
    float T     = nzmax - margin;
    float wT    = __expf(-T);
    float uthr  = __expf(-(wT - 1e-8f)) - 1e-8f;
    uthr = uthr - fabsf(uthr) * 1e-5f - 1e-9f;   // downward: inclusive filter

    // ---- scan M[]; qualifying j re-loads its float4 and pushes candidates ----
    if (active) {
        #pragma unroll
        for (int j = 0; j < 15; j++) {
            if (M[j] >= uthr) {
                const int f = j * 16 + lane16;
                const bool valid = (j < 14) || (lane16 == 0);
                const int fc = valid ? f : 0;
                float4 u = g4[fc];                 // L1/L2-hot re-read
                if (!valid) { u.x = u.y = u.z = u.w = -1.0f; }
                const int s0 = fc * 4;
                if (u.x >= uthr) { int i2 = atomicAdd(&s_cnt, 1); if (i2 < CAP) { s_qs[i2] = (gg << 10) | s0;       s_qu[i2] = u.x; } }
                if (u.y >= uthr) { int i2 = atomicAdd(&s_cnt, 1); if (i2 < CAP) { s_qs[i2] = (gg << 10) | (s0 + 1); s_qu[i2] = u.y; } }
                if (u.z >= uthr) { int i2 = atomicAdd(&s_cnt, 1); if (i2 < CAP) { s_qs[i2] = (gg << 10) | (s0 + 2); s_qu[i2] = u.z; } }
                if (u.w >= uthr) { int i2 = atomicAdd(&s_cnt, 1); if (i2 < CAP) { s_qs[i2] = (gg << 10) | (s0 + 3); s_qu[i2] = u.w; } }
            }
        }
    }
    __syncthreads();

    // ---- ONE convergent precise eval pass over the block's candidates ----
    const int nc = min(s_cnt, CAP);
    if (tid < nc) {
        int   pk = s_qs[tid];
        int   g2 = pk >> 10, s = pk & 0x3FF;
        float u  = s_qu[tid];
        float q2 = s_q[g2], m2 = s_m[g2], D2 = s_D[g2];
        float l  = __fmul_rn(q2, kf[s]);
        float nz = -logf(-logf(u + 1e-8f) + 1e-8f);
        float v  = expf(l - m2) / D2 + nz;
        unsigned vb = __float_as_uint(v);
        unsigned key32 = (vb & 0x80000000u) ? ~vb : (vb | 0x80000000u);
        unsigned long long key =
            ((unsigned long long)key32 << 32) | (unsigned)(0xFFFFFFFFu - (unsigned)s);
        atomicMax(&s_win[g2], key);
    }
    __syncthreads();

    if (active && lane16 == 0) {
        unsigned long long key = s_win[gg];
        unsigned s = 0xFFFFFFFFu - (unsigned)(key & 0xFFFFFFFFull);
        idxbuf[n * SS + t] = (int)s;
    }
}

// One block per n: gather radar[t] into acc[idx[t]] via LDS atomics, then
// write EVERY out element with the epilogue fused (no pre-zero, no RMW):
// out[b,s,w] = acc[s] + (radar[s]!=0 && acc[s]!=0) * scale*beta
__global__ __launch_bounds__(1024) void rel_final(
    const float* __restrict__ radar,   // [W,B,900]
    const int* __restrict__ idxbuf,    // [64][900]
    const float* __restrict__ pScale,
    const float* __restrict__ pBeta,
    float* __restrict__ out)           // [B,900,W]
{
    const int n = blockIdx.x;
    const int b = n >> 3, w = n & 7;
    const int tid = threadIdx.x;

    __shared__ float acc[SS];
    __shared__ float rad[SS];

    if (tid < SS) {
        acc[tid] = 0.0f;
        rad[tid] = radar[(size_t)(w * BD + b) * SS + tid];
    }
    __syncthreads();
    if (tid < SS) {
        int s = idxbuf[n * SS + tid];
        atomicAdd(&acc[s], rad[tid]);
    }
    __syncthreads();
    if (tid < SS) {
        const float c = pScale[0] * pBeta[0];
        float o = acc[tid];
        float r = rad[tid];
        out[((size_t)b * SS + tid) * WD + w] =
            o + (((r != 0.0f) && (o != 0.0f)) ? c : 0.0f);
    }
}

extern "C" void kernel_launch(void* const* d_in, const int* in_sizes, int n_in,
                              void* d_out, int out_size, void* d_ws, size_t ws_size,
                              hipStream_t stream) {
    const float* radar  = (const float*)d_in[0];
    const float* mde    = (const float*)d_in[1];
    const float* gumbel = (const float*)d_in[2];
    const float* Wq     = (const float*)d_in[3];
    const float* bq     = (const float*)d_in[4];
    const float* Wk     = (const float*)d_in[5];
    const float* bk     = (const float*)d_in[6];
    // d_in[7..11] = Wv, bv, Wo, bo, ln_gamma (dead: LN over dim-1 => attended_out == ln_beta)
    const float* beta   = (const float*)d_in[12];
    const float* scale  = (const float*)d_in[13];
    float* out = (float*)d_out;

    int* idxbuf = (int*)d_ws;          // [64][900], fully overwritten each call

    rel_main<<<NROWS * BLKS_PER_N, 256, 0, stream>>>(radar, mde, gumbel,
                                                     Wq, bq, Wk, bk, idxbuf);
    rel_final<<<NROWS, 1024, 0, stream>>>(radar, idxbuf, scale, beta, out);
}